// Round 3
// baseline (435.602 us; speedup 1.0000x reference)
//
#include <hip/hip_runtime.h>
#include <math.h>

#define BB 8
#define LL 2048
#define DD 128
#define HH 4
#define DKK 32
#define DFFF 256

#define NEGMIN (-3.402823466e38f)
#define LOG2E 1.44269504088896f

typedef _Float16 f16;
typedef _Float16 f16x8 __attribute__((ext_vector_type(8)));
typedef float f32x4 __attribute__((ext_vector_type(4)));

// ---------------- QKV projection (f32 in -> f16 q,k + f16 transposed v) ----
__global__ __launch_bounds__(384) void qkv_kernel(
    const float* __restrict__ x,
    const float* __restrict__ Wq, const float* __restrict__ Wk,
    const float* __restrict__ Wv,
    f16* __restrict__ qh, f16* __restrict__ kh, f16* __restrict__ vth) {
  __shared__ float xs[16][128];
  const int t = threadIdx.x;
  const long r0 = (long)blockIdx.x * 16;
  for (int idx = t; idx < 16 * 128; idx += 384)
    xs[idx >> 7][idx & 127] = x[r0 * 128 + idx];
  __syncthreads();

  const int sel = t >> 7;       // 0=q 1=k 2=v
  const int jj = t & 127;
  const int h = jj >> 5, e = jj & 31;
  const float* W = (sel == 0) ? Wq : (sel == 1) ? Wk : Wv;
  const float* Wbase = W + (h * 128) * 32 + e;   // [H,D,DK]
  float acc[16];
#pragma unroll
  for (int r = 0; r < 16; ++r) acc[r] = 0.f;
  for (int d = 0; d < 128; ++d) {
    const float w = Wbase[d * 32];
#pragma unroll
    for (int r = 0; r < 16; ++r) acc[r] += xs[r][d] * w;
  }
  const int b = (int)(r0 >> 11);
  const int l0 = (int)(r0 & 2047);
  const int bh = b * HH + h;
  if (sel == 2) {
    f16 tmp[16];
#pragma unroll
    for (int r = 0; r < 16; ++r) tmp[r] = (f16)acc[r];
    f16* base = vth + ((size_t)bh * DKK + e) * LL + l0;
    *(f16x8*)(base) = *(f16x8*)&tmp[0];
    *(f16x8*)(base + 8) = *(f16x8*)&tmp[8];
  } else {
    f16* out = (sel == 0) ? qh : kh;
#pragma unroll
    for (int r = 0; r < 16; ++r)
      out[((size_t)bh * LL + (l0 + r)) * DKK + e] = (f16)acc[r];
  }
}

// ---------------- Flash attention via f16 MFMA ----------------
// grid: (L/64, B*H), 256 threads (4 waves). Wave handles 16 q-rows.
// K/V tiles of 64 double-buffered in LDS, reg-staged (issue-early/commit-late).
__global__ __launch_bounds__(256) void attn_kernel(
    const f16* __restrict__ qh, const f16* __restrict__ kh,
    const f16* __restrict__ vth, const float* __restrict__ mask,
    float* __restrict__ o) {
  __shared__ f16 Ks[2][64][40];
  __shared__ f16 Vt[2][32][72];
  __shared__ f16 Ps[4][16][72];
  __shared__ float mks[2][64];
  const int t = threadIdx.x;
  const int wave = t >> 6, lane = t & 63;
  const int g = lane >> 4, c = lane & 15;
  const int bh = blockIdx.y;
  const int b = bh >> 2;
  const int qw = blockIdx.x * 64 + wave * 16;

  // Q fragment (A operand), in registers for the whole kernel
  const f16x8 qfrag =
      *(const f16x8*)(qh + ((size_t)bh * LL + qw + c) * DKK + g * 8);
  float mqv[4];
#pragma unroll
  for (int r = 0; r < 4; ++r) mqv[r] = mask[b * LL + qw + g * 4 + r];

  f32x4 o4[2];
  float m[4], l[4];
#pragma unroll
  for (int r = 0; r < 4; ++r) {
    o4[0][r] = 0.f; o4[1][r] = 0.f;
    m[r] = -3.0e38f; l[r] = 0.f;
  }

  const f16* kbase = kh + (size_t)bh * LL * DKK;
  const f16* vbase = vth + (size_t)bh * DKK * LL;
  const int krow = t >> 2, kch = t & 3;   // 64 rows x 4 chunks
  const int vd = t >> 3, vseg = t & 7;    // 32 d-rows x 8 segs

  // prologue: stage tile 0
  f16x8 kreg = *(const f16x8*)(kbase + (size_t)krow * DKK + kch * 8);
  f16x8 vreg = *(const f16x8*)(vbase + (size_t)vd * LL + vseg * 8);
  float mreg = (t < 64) ? mask[b * LL + t] : 0.f;
  *(f16x8*)&Ks[0][krow][kch * 8] = kreg;
  *(f16x8*)&Vt[0][vd][vseg * 8] = vreg;
  if (t < 64) mks[0][t] = mreg;
  __syncthreads();

  for (int kt = 0; kt < LL / 64; ++kt) {
    const int cur = kt & 1;
    // issue next tile's global loads early (latency hides under compute)
    if (kt < LL / 64 - 1) {
      const int k0 = (kt + 1) * 64;
      kreg = *(const f16x8*)(kbase + (size_t)(k0 + krow) * DKK + kch * 8);
      vreg = *(const f16x8*)(vbase + (size_t)vd * LL + k0 + vseg * 8);
      if (t < 64) mreg = mask[b * LL + k0 + t];
    }

    // ---- QK^T ----
    f16x8 kb[4];
#pragma unroll
    for (int nt = 0; nt < 4; ++nt)
      kb[nt] = *(const f16x8*)&Ks[cur][c + nt * 16][g * 8];
    f32x4 s[4];
#pragma unroll
    for (int nt = 0; nt < 4; ++nt) {
      f32x4 z = {0.f, 0.f, 0.f, 0.f};
      s[nt] = __builtin_amdgcn_mfma_f32_16x16x32_f16(qfrag, kb[nt], z, 0, 0, 0);
    }
    float mkv[4];
#pragma unroll
    for (int nt = 0; nt < 4; ++nt) mkv[nt] = mks[cur][c + nt * 16];
#pragma unroll
    for (int nt = 0; nt < 4; ++nt)
#pragma unroll
      for (int r = 0; r < 4; ++r)
        s[nt][r] += (1.f - mqv[r] * mkv[nt]) * NEGMIN;

    // ---- online softmax ----
#pragma unroll
    for (int r = 0; r < 4; ++r) {
      float vmax = fmaxf(fmaxf(s[0][r], s[1][r]), fmaxf(s[2][r], s[3][r]));
      vmax = fmaxf(vmax, __shfl_xor(vmax, 1));
      vmax = fmaxf(vmax, __shfl_xor(vmax, 2));
      vmax = fmaxf(vmax, __shfl_xor(vmax, 4));
      vmax = fmaxf(vmax, __shfl_xor(vmax, 8));
      const float mn = fmaxf(m[r], vmax);
      const float sc = __builtin_exp2f((m[r] - mn) * LOG2E);
      const float mn2 = mn * LOG2E;
      float ps = 0.f;
#pragma unroll
      for (int nt = 0; nt < 4; ++nt) {
        const float p = __builtin_exp2f(fmaf(s[nt][r], LOG2E, -mn2));
        ps += p;
        Ps[wave][g * 4 + r][c + nt * 16] = (f16)p;
      }
      ps += __shfl_xor(ps, 1);
      ps += __shfl_xor(ps, 2);
      ps += __shfl_xor(ps, 4);
      ps += __shfl_xor(ps, 8);
      l[r] = l[r] * sc + ps;
      m[r] = mn;
      o4[0][r] *= sc;
      o4[1][r] *= sc;
    }

    // ---- PV ---- (P is wave-private)
    f16x8 pa[2], vb2[2][2];
#pragma unroll
    for (int hf = 0; hf < 2; ++hf)
      pa[hf] = *(const f16x8*)&Ps[wave][c][hf * 32 + g * 8];
#pragma unroll
    for (int dt = 0; dt < 2; ++dt)
#pragma unroll
      for (int hf = 0; hf < 2; ++hf)
        vb2[dt][hf] = *(const f16x8*)&Vt[cur][dt * 16 + c][hf * 32 + g * 8];
#pragma unroll
    for (int dt = 0; dt < 2; ++dt) {
      o4[dt] = __builtin_amdgcn_mfma_f32_16x16x32_f16(pa[0], vb2[dt][0], o4[dt], 0, 0, 0);
      o4[dt] = __builtin_amdgcn_mfma_f32_16x16x32_f16(pa[1], vb2[dt][1], o4[dt], 0, 0, 0);
    }

    // commit next tile to the other buffer
    if (kt < LL / 64 - 1) {
      *(f16x8*)&Ks[1 - cur][krow][kch * 8] = kreg;
      *(f16x8*)&Vt[1 - cur][vd][vseg * 8] = vreg;
      if (t < 64) mks[1 - cur][t] = mreg;
    }
    __syncthreads();
  }

  // ---- epilogue ----
  const int h = bh & 3;
  float rdiv[4];
#pragma unroll
  for (int r = 0; r < 4; ++r) rdiv[r] = 1.f / l[r];
#pragma unroll
  for (int dt = 0; dt < 2; ++dt)
#pragma unroll
    for (int r = 0; r < 4; ++r) {
      const int row = qw + g * 4 + r;
      o[((size_t)b * LL + row) * DD + h * DKK + dt * 16 + c] =
          o4[dt][r] * rdiv[r];
    }
}

// ---------------- fused oproj + residual + FFN (gelu) + residual ----------
// 16 rows per block, 256 threads. xmid and f stay in LDS.
__global__ __launch_bounds__(256) void mlp_kernel(
    const float* __restrict__ o, const float* __restrict__ x,
    const float* __restrict__ Wo, const float* __restrict__ W1,
    const float* __restrict__ b1, const float* __restrict__ W2,
    const float* __restrict__ b2, float* __restrict__ xout) {
  __shared__ float os[16][128];
  __shared__ float xm[16][128];
  __shared__ float fs[16][256];
  const int t = threadIdx.x;
  const long r0 = (long)blockIdx.x * 16;
  for (int idx = t; idx < 2048; idx += 256)
    os[idx >> 7][idx & 127] = o[r0 * 128 + idx];
  __syncthreads();

  const int jj = t & 127, rh = t >> 7;
  // ---- o @ Wo + residual ----
  {
    float acc[8];
#pragma unroll
    for (int r = 0; r < 8; ++r) acc[r] = 0.f;
    for (int d = 0; d < 128; ++d) {
      const float w = Wo[d * 128 + jj];
#pragma unroll
      for (int r = 0; r < 8; ++r) acc[r] += os[rh * 8 + r][d] * w;
    }
#pragma unroll
    for (int r = 0; r < 8; ++r) {
      const int row = rh * 8 + r;
      xm[row][jj] = (acc[r] + x[(r0 + row) * 128 + jj]) * 0.5f;
    }
  }
  __syncthreads();

  // ---- FFN1 + exact GELU ----
  {
    float acc[16];
#pragma unroll
    for (int r = 0; r < 16; ++r) acc[r] = 0.f;
    for (int d = 0; d < 128; ++d) {
      const float w = W1[d * 256 + t];
#pragma unroll
      for (int r = 0; r < 16; ++r) acc[r] += xm[r][d] * w;
    }
    const float bj = b1[t];
#pragma unroll
    for (int r = 0; r < 16; ++r) {
      const float val = acc[r] + bj;
      fs[r][t] = 0.5f * val * (1.f + erff(val * 0.70710678118654752f));
    }
  }
  __syncthreads();

  // ---- FFN2 + bias + residual ----
  {
    float acc[8];
#pragma unroll
    for (int r = 0; r < 8; ++r) acc[r] = 0.f;
    for (int d = 0; d < 256; ++d) {
      const float w = W2[d * 128 + jj];
#pragma unroll
      for (int r = 0; r < 8; ++r) acc[r] += fs[rh * 8 + r][d] * w;
    }
    const float bj = b2[jj];
#pragma unroll
    for (int r = 0; r < 8; ++r) {
      const int row = rh * 8 + r;
      xout[(r0 + row) * 128 + jj] = (acc[r] + bj + xm[row][jj]) * 0.5f;
    }
  }
}

extern "C" void kernel_launch(void* const* d_in, const int* in_sizes, int n_in,
                              void* d_out, int out_size, void* d_ws,
                              size_t ws_size, hipStream_t stream) {
  const float* x    = (const float*)d_in[0];
  const float* mask = (const float*)d_in[1];
  const float* Wq   = (const float*)d_in[2];
  const float* Wk   = (const float*)d_in[3];
  const float* Wv   = (const float*)d_in[4];
  const float* Wo   = (const float*)d_in[5];
  const float* W1   = (const float*)d_in[6];
  const float* b1   = (const float*)d_in[7];
  const float* W2   = (const float*)d_in[8];
  const float* b2   = (const float*)d_in[9];

  const size_t SZ = (size_t)BB * LL * DD;
  char* p = (char*)d_ws;
  f16* qh   = (f16*)p;  p += SZ * sizeof(f16);
  f16* kh   = (f16*)p;  p += SZ * sizeof(f16);
  f16* vth  = (f16*)p;  p += SZ * sizeof(f16);
  float* ob = (float*)p;  p += SZ * sizeof(float);
  float* xA = (float*)p;

  const int rowBlocks = (BB * LL) / 16;   // 1024

  for (int i = 0; i < 2; ++i) {
    const float* xin = (i == 0) ? x : xA;
    float* xout = (i == 1) ? (float*)d_out : xA;
    const float* Wq_i = Wq + (long)i * HH * DD * DKK;
    const float* Wk_i = Wk + (long)i * HH * DD * DKK;
    const float* Wv_i = Wv + (long)i * HH * DD * DKK;
    const float* Wo_i = Wo + (long)i * DD * DD;
    const float* W1_i = W1 + (long)i * DD * DFFF;
    const float* b1_i = b1 + (long)i * DFFF;
    const float* W2_i = W2 + (long)i * DFFF * DD;
    const float* b2_i = b2 + (long)i * DD;

    qkv_kernel<<<rowBlocks, 384, 0, stream>>>(xin, Wq_i, Wk_i, Wv_i, qh, kh, vth);
    attn_kernel<<<dim3(LL / 64, BB * HH), 256, 0, stream>>>(qh, kh, vth, mask, ob);
    mlp_kernel<<<rowBlocks, 256, 0, stream>>>(ob, xin, Wo_i, W1_i, b1_i, W2_i, b2_i, xout);
  }
}

// Round 5
// 375.855 us; speedup vs baseline: 1.1590x; 1.1590x over previous
//
#include <hip/hip_runtime.h>
#include <math.h>

#define BB 8
#define LL 2048
#define DD 128
#define HH 4
#define DKK 32
#define DFFF 256

#define NEGMIN (-3.402823466e38f)
#define LOG2E 1.44269504088896f

typedef _Float16 f16;
typedef _Float16 f16x4 __attribute__((ext_vector_type(4)));
typedef _Float16 f16x8 __attribute__((ext_vector_type(8)));
typedef float f32x4 __attribute__((ext_vector_type(4)));

// ---------------- QKV projection (f32 in -> f16 q,k + f16 transposed v) ----
__global__ __launch_bounds__(384) void qkv_kernel(
    const float* __restrict__ x,
    const float* __restrict__ Wq, const float* __restrict__ Wk,
    const float* __restrict__ Wv,
    f16* __restrict__ qh, f16* __restrict__ kh, f16* __restrict__ vth) {
  __shared__ float xs[16][128];
  const int t = threadIdx.x;
  const long r0 = (long)blockIdx.x * 16;
  for (int idx = t; idx < 16 * 128; idx += 384)
    xs[idx >> 7][idx & 127] = x[r0 * 128 + idx];
  __syncthreads();

  const int sel = t >> 7;       // 0=q 1=k 2=v
  const int jj = t & 127;
  const int h = jj >> 5, e = jj & 31;
  const float* W = (sel == 0) ? Wq : (sel == 1) ? Wk : Wv;
  const float* Wbase = W + (h * 128) * 32 + e;   // [H,D,DK]
  float acc[16];
#pragma unroll
  for (int r = 0; r < 16; ++r) acc[r] = 0.f;
  for (int d = 0; d < 128; ++d) {
    const float w = Wbase[d * 32];
#pragma unroll
    for (int r = 0; r < 16; ++r) acc[r] += xs[r][d] * w;
  }
  const int b = (int)(r0 >> 11);
  const int l0 = (int)(r0 & 2047);
  const int bh = b * HH + h;
  if (sel == 2) {
    f16 tmp[16];
#pragma unroll
    for (int r = 0; r < 16; ++r) tmp[r] = (f16)acc[r];
    f16* base = vth + ((size_t)bh * DKK + e) * LL + l0;
    *(f16x8*)(base) = *(f16x8*)&tmp[0];
    *(f16x8*)(base + 8) = *(f16x8*)&tmp[8];
  } else {
    f16* out = (sel == 0) ? qh : kh;
#pragma unroll
    for (int r = 0; r < 16; ++r)
      out[((size_t)bh * LL + (l0 + r)) * DKK + e] = (f16)acc[r];
  }
}

// ---------------- Flash attention, S^T-layout (register-resident P) -------
// grid: (L/128, B*H), 256 threads (4 waves). Wave handles 32 q-rows
// (2 q-tiles of 16). KV tiles of 64 double-buffered in LDS, reg-staged.
// S^T = mfma(K,Q): lane holds 16 logits of ONE q-row (q = lane&15).
// P^T in registers is directly the B-operand of 16x16x16 PV MFMA.
__global__ __launch_bounds__(256) void attn_kernel(
    const f16* __restrict__ qh, const f16* __restrict__ kh,
    const f16* __restrict__ vth, const float* __restrict__ mask,
    float* __restrict__ o) {
  __shared__ f16 Ks[2][64][40];
  __shared__ f16 Vt[2][32][72];
  __shared__ float mks[2][64];
  const int t = threadIdx.x;
  const int wave = t >> 6, lane = t & 63;
  const int g = lane >> 4, c = lane & 15;
  const int bh = blockIdx.y;
  const int b = bh >> 2;
  const int qw = blockIdx.x * 128 + wave * 32;

  // Q fragments: B-operand layout (n=q=lane&15, k=8g+j) == A layout
  f16x8 qfrag[2];
  float mqv[2];
#pragma unroll
  for (int qt = 0; qt < 2; ++qt) {
    qfrag[qt] =
        *(const f16x8*)(qh + ((size_t)bh * LL + qw + qt * 16 + c) * DKK + g * 8);
    mqv[qt] = mask[b * LL + qw + qt * 16 + c];
  }

  // O^T accumulators: [qt][dt], row = dv = 16dt+4g+r, col = q = c
  f32x4 o4[2][2];
  float m[2], l[2];
#pragma unroll
  for (int qt = 0; qt < 2; ++qt) {
    m[qt] = -3.0e38f; l[qt] = 0.f;
#pragma unroll
    for (int dt = 0; dt < 2; ++dt)
#pragma unroll
      for (int r = 0; r < 4; ++r) o4[qt][dt][r] = 0.f;
  }

  const f16* kbase = kh + (size_t)bh * LL * DKK;
  const f16* vbase = vth + (size_t)bh * DKK * LL;
  const int krow = t >> 2, kch = t & 3;   // 64 rows x 4 chunks of 8 f16
  const int vd = t >> 3, vseg = t & 7;    // 32 d-rows x 8 segs of 8 f16

  // prologue: stage tile 0
  f16x8 kreg = *(const f16x8*)(kbase + (size_t)krow * DKK + kch * 8);
  f16x8 vreg = *(const f16x8*)(vbase + (size_t)vd * LL + vseg * 8);
  float mreg = (t < 64) ? mask[b * LL + t] : 0.f;
  *(f16x8*)&Ks[0][krow][kch * 8] = kreg;
  *(f16x8*)&Vt[0][vd][vseg * 8] = vreg;
  if (t < 64) mks[0][t] = mreg;
  __syncthreads();

  for (int kt = 0; kt < LL / 64; ++kt) {
    const int cur = kt & 1;
    if (kt < LL / 64 - 1) {   // issue next tile's loads early
      const int k0 = (kt + 1) * 64;
      kreg = *(const f16x8*)(kbase + (size_t)(k0 + krow) * DKK + kch * 8);
      vreg = *(const f16x8*)(vbase + (size_t)vd * LL + k0 + vseg * 8);
      if (t < 64) mreg = mask[b * LL + k0 + t];
    }

    // ---- QK^T (swapped): S^T[kv=16nt+4g+r][q=c] ----
    f16x8 kb[4];
#pragma unroll
    for (int nt = 0; nt < 4; ++nt)
      kb[nt] = *(const f16x8*)&Ks[cur][nt * 16 + c][g * 8];
    f32x4 st[2][4];
#pragma unroll
    for (int qt = 0; qt < 2; ++qt)
#pragma unroll
      for (int nt = 0; nt < 4; ++nt) {
        f32x4 z = {0.f, 0.f, 0.f, 0.f};
        st[qt][nt] =
            __builtin_amdgcn_mfma_f32_16x16x32_f16(kb[nt], qfrag[qt], z, 0, 0, 0);
      }

    // ---- mask add ----
    float4 mk4[4];
#pragma unroll
    for (int nt = 0; nt < 4; ++nt)
      mk4[nt] = *(const float4*)&mks[cur][nt * 16 + 4 * g];
#pragma unroll
    for (int qt = 0; qt < 2; ++qt) {
      const float mq = mqv[qt];
#pragma unroll
      for (int nt = 0; nt < 4; ++nt) {
        st[qt][nt][0] += (1.f - mq * mk4[nt].x) * NEGMIN;
        st[qt][nt][1] += (1.f - mq * mk4[nt].y) * NEGMIN;
        st[qt][nt][2] += (1.f - mq * mk4[nt].z) * NEGMIN;
        st[qt][nt][3] += (1.f - mq * mk4[nt].w) * NEGMIN;
      }
    }

    // ---- softmax + PV per q-tile ----
    f16x4 va[2][4];
#pragma unroll
    for (int dt = 0; dt < 2; ++dt)
#pragma unroll
      for (int nt = 0; nt < 4; ++nt)
        va[dt][nt] = *(const f16x4*)&Vt[cur][dt * 16 + c][nt * 16 + 4 * g];

#pragma unroll
    for (int qt = 0; qt < 2; ++qt) {
      // row max over 16 in-register values + 2 shfls
      float mx01 = fmaxf(fmaxf(st[qt][0][0], st[qt][0][1]),
                         fmaxf(st[qt][0][2], st[qt][0][3]));
      float mx23 = fmaxf(fmaxf(st[qt][1][0], st[qt][1][1]),
                         fmaxf(st[qt][1][2], st[qt][1][3]));
      float mx45 = fmaxf(fmaxf(st[qt][2][0], st[qt][2][1]),
                         fmaxf(st[qt][2][2], st[qt][2][3]));
      float mx67 = fmaxf(fmaxf(st[qt][3][0], st[qt][3][1]),
                         fmaxf(st[qt][3][2], st[qt][3][3]));
      float vmax = fmaxf(fmaxf(mx01, mx23), fmaxf(mx45, mx67));
      vmax = fmaxf(vmax, __shfl_xor(vmax, 16));
      vmax = fmaxf(vmax, __shfl_xor(vmax, 32));
      const float mn = fmaxf(m[qt], vmax);
      const float sc = __builtin_exp2f((m[qt] - mn) * LOG2E);
      const float mn2 = mn * LOG2E;
      m[qt] = mn;

      float p[4][4];
      float psum = 0.f;
#pragma unroll
      for (int nt = 0; nt < 4; ++nt) {
        float s0 = 0.f;
#pragma unroll
        for (int r = 0; r < 4; ++r) {
          p[nt][r] = __builtin_exp2f(fmaf(st[qt][nt][r], LOG2E, -mn2));
          s0 += p[nt][r];
        }
        psum += s0;
      }
      psum += __shfl_xor(psum, 16);
      psum += __shfl_xor(psum, 32);
      l[qt] = l[qt] * sc + psum;

#pragma unroll
      for (int dt = 0; dt < 2; ++dt)
#pragma unroll
        for (int r = 0; r < 4; ++r) o4[qt][dt][r] *= sc;

      // pack P to f16: B-operand fragment (n=q=c, k=4g+j) per nt
#pragma unroll
      for (int nt = 0; nt < 4; ++nt) {
        f16x4 pk;
        pk[0] = (f16)p[nt][0];
        pk[1] = (f16)p[nt][1];
        pk[2] = (f16)p[nt][2];
        pk[3] = (f16)p[nt][3];
#pragma unroll
        for (int dt = 0; dt < 2; ++dt)
          o4[qt][dt] = __builtin_amdgcn_mfma_f32_16x16x16f16(
              va[dt][nt], pk, o4[qt][dt], 0, 0, 0);
      }
    }

    // commit next tile to the other buffer
    if (kt < LL / 64 - 1) {
      *(f16x8*)&Ks[1 - cur][krow][kch * 8] = kreg;
      *(f16x8*)&Vt[1 - cur][vd][vseg * 8] = vreg;
      if (t < 64) mks[1 - cur][t] = mreg;
    }
    __syncthreads();
  }

  // ---- epilogue: lane (c,g) holds O^T[dv=16dt+4g+r][q=qw+16qt+c] ----
  const int h = bh & 3;
#pragma unroll
  for (int qt = 0; qt < 2; ++qt) {
    const float rdiv = 1.f / l[qt];
    float* orow = o + ((size_t)b * LL + qw + qt * 16 + c) * DD + h * DKK;
#pragma unroll
    for (int dt = 0; dt < 2; ++dt) {
      float4 res;
      res.x = o4[qt][dt][0] * rdiv;
      res.y = o4[qt][dt][1] * rdiv;
      res.z = o4[qt][dt][2] * rdiv;
      res.w = o4[qt][dt][3] * rdiv;
      *(float4*)(orow + dt * 16 + g * 4) = res;
    }
  }
}

// ---------------- fused oproj + residual + FFN (gelu) + residual ----------
__global__ __launch_bounds__(256) void mlp_kernel(
    const float* __restrict__ o, const float* __restrict__ x,
    const float* __restrict__ Wo, const float* __restrict__ W1,
    const float* __restrict__ b1, const float* __restrict__ W2,
    const float* __restrict__ b2, float* __restrict__ xout) {
  __shared__ float os[16][128];
  __shared__ float xm[16][128];
  __shared__ float fs[16][256];
  const int t = threadIdx.x;
  const long r0 = (long)blockIdx.x * 16;
  for (int idx = t; idx < 2048; idx += 256)
    os[idx >> 7][idx & 127] = o[r0 * 128 + idx];
  __syncthreads();

  const int jj = t & 127, rh = t >> 7;
  {
    float acc[8];
#pragma unroll
    for (int r = 0; r < 8; ++r) acc[r] = 0.f;
    for (int d = 0; d < 128; ++d) {
      const float w = Wo[d * 128 + jj];
#pragma unroll
      for (int r = 0; r < 8; ++r) acc[r] += os[rh * 8 + r][d] * w;
    }
#pragma unroll
    for (int r = 0; r < 8; ++r) {
      const int row = rh * 8 + r;
      xm[row][jj] = (acc[r] + x[(r0 + row) * 128 + jj]) * 0.5f;
    }
  }
  __syncthreads();
  {
    float acc[16];
#pragma unroll
    for (int r = 0; r < 16; ++r) acc[r] = 0.f;
    for (int d = 0; d < 128; ++d) {
      const float w = W1[d * 256 + t];
#pragma unroll
      for (int r = 0; r < 16; ++r) acc[r] += xm[r][d] * w;
    }
    const float bj = b1[t];
#pragma unroll
    for (int r = 0; r < 16; ++r) {
      const float val = acc[r] + bj;
      fs[r][t] = 0.5f * val * (1.f + erff(val * 0.70710678118654752f));
    }
  }
  __syncthreads();
  {
    float acc[8];
#pragma unroll
    for (int r = 0; r < 8; ++r) acc[r] = 0.f;
    for (int d = 0; d < 256; ++d) {
      const float w = W2[d * 128 + jj];
#pragma unroll
      for (int r = 0; r < 8; ++r) acc[r] += fs[rh * 8 + r][d] * w;
    }
    const float bj = b2[jj];
#pragma unroll
    for (int r = 0; r < 8; ++r) {
      const int row = rh * 8 + r;
      xout[(r0 + row) * 128 + jj] = (acc[r] + bj + xm[row][jj]) * 0.5f;
    }
  }
}

extern "C" void kernel_launch(void* const* d_in, const int* in_sizes, int n_in,
                              void* d_out, int out_size, void* d_ws,
                              size_t ws_size, hipStream_t stream) {
  const float* x    = (const float*)d_in[0];
  const float* mask = (const float*)d_in[1];
  const float* Wq   = (const float*)d_in[2];
  const float* Wk   = (const float*)d_in[3];
  const float* Wv   = (const float*)d_in[4];
  const float* Wo   = (const float*)d_in[5];
  const float* W1   = (const float*)d_in[6];
  const float* b1   = (const float*)d_in[7];
  const float* W2   = (const float*)d_in[8];
  const float* b2   = (const float*)d_in[9];

  const size_t SZ = (size_t)BB * LL * DD;
  char* p = (char*)d_ws;
  f16* qh   = (f16*)p;  p += SZ * sizeof(f16);
  f16* kh   = (f16*)p;  p += SZ * sizeof(f16);
  f16* vth  = (f16*)p;  p += SZ * sizeof(f16);
  float* ob = (float*)p;  p += SZ * sizeof(float);
  float* xA = (float*)p;

  const int rowBlocks = (BB * LL) / 16;   // 1024

  for (int i = 0; i < 2; ++i) {
    const float* xin = (i == 0) ? x : xA;
    float* xout = (i == 1) ? (float*)d_out : xA;
    const float* Wq_i = Wq + (long)i * HH * DD * DKK;
    const float* Wk_i = Wk + (long)i * HH * DD * DKK;
    const float* Wv_i = Wv + (long)i * HH * DD * DKK;
    const float* Wo_i = Wo + (long)i * DD * DD;
    const float* W1_i = W1 + (long)i * DD * DFFF;
    const float* b1_i = b1 + (long)i * DFFF;
    const float* W2_i = W2 + (long)i * DFFF * DD;
    const float* b2_i = b2 + (long)i * DD;

    qkv_kernel<<<rowBlocks, 384, 0, stream>>>(xin, Wq_i, Wk_i, Wv_i, qh, kh, vth);
    attn_kernel<<<dim3(LL / 128, BB * HH), 256, 0, stream>>>(qh, kh, vth, mask, ob);
    mlp_kernel<<<rowBlocks, 256, 0, stream>>>(ob, xin, Wo_i, W1_i, b1_i, W2_i, b2_i, xout);
  }
}

// Round 6
// 276.248 us; speedup vs baseline: 1.5768x; 1.3606x over previous
//
#include <hip/hip_runtime.h>
#include <math.h>

#define BB 8
#define LL 2048
#define DD 128
#define HH 4
#define DKK 32
#define DFFF 256

#define NEGMIN (-3.402823466e38f)
#define LOG2E 1.44269504088896f

typedef _Float16 f16;
typedef _Float16 f16x4 __attribute__((ext_vector_type(4)));
typedef _Float16 f16x8 __attribute__((ext_vector_type(8)));
typedef float f32x4 __attribute__((ext_vector_type(4)));

// ---------------- QKV projection (f32 in -> f16 q,k + f16 transposed v) ----
__global__ __launch_bounds__(384) void qkv_kernel(
    const float* __restrict__ x,
    const float* __restrict__ Wq, const float* __restrict__ Wk,
    const float* __restrict__ Wv,
    f16* __restrict__ qh, f16* __restrict__ kh, f16* __restrict__ vth) {
  __shared__ float xs[16][128];
  const int t = threadIdx.x;
  const long r0 = (long)blockIdx.x * 16;
  for (int idx = t; idx < 16 * 128; idx += 384)
    xs[idx >> 7][idx & 127] = x[r0 * 128 + idx];
  __syncthreads();

  const int sel = t >> 7;       // 0=q 1=k 2=v
  const int jj = t & 127;
  const int h = jj >> 5, e = jj & 31;
  const float* W = (sel == 0) ? Wq : (sel == 1) ? Wk : Wv;
  const float* Wbase = W + (h * 128) * 32 + e;   // [H,D,DK]
  float acc[16];
#pragma unroll
  for (int r = 0; r < 16; ++r) acc[r] = 0.f;
  for (int d = 0; d < 128; ++d) {
    const float w = Wbase[d * 32];
#pragma unroll
    for (int r = 0; r < 16; ++r) acc[r] += xs[r][d] * w;
  }
  const int b = (int)(r0 >> 11);
  const int l0 = (int)(r0 & 2047);
  const int bh = b * HH + h;
  if (sel == 2) {
    f16 tmp[16];
#pragma unroll
    for (int r = 0; r < 16; ++r) tmp[r] = (f16)acc[r];
    f16* base = vth + ((size_t)bh * DKK + e) * LL + l0;
    *(f16x8*)(base) = *(f16x8*)&tmp[0];
    *(f16x8*)(base + 8) = *(f16x8*)&tmp[8];
  } else {
    f16* out = (sel == 0) ? qh : kh;
#pragma unroll
    for (int r = 0; r < 16; ++r)
      out[((size_t)bh * LL + (l0 + r)) * DKK + e] = (f16)acc[r];
  }
}

// ---------------- weight convert: Wo/W1/W2 -> f16 transposed [n][k] -------
// per layer: [0,16384) WoT, [16384,49152) W1T, [49152,81920) W2T
__global__ __launch_bounds__(256) void wconv_kernel(
    const float* __restrict__ Wo, const float* __restrict__ W1,
    const float* __restrict__ W2, f16* __restrict__ wt) {
  const int idx = blockIdx.x * 256 + threadIdx.x;
  const int i = idx / 81920;
  const int r = idx % 81920;
  float val;
  if (r < 16384) {
    const int n = r >> 7, k = r & 127;
    val = Wo[i * 16384 + k * 128 + n];
  } else if (r < 49152) {
    const int r2 = r - 16384;
    const int n = r2 >> 7, k = r2 & 127;
    val = W1[i * 32768 + k * 256 + n];
  } else {
    const int r2 = r - 49152;
    const int n = r2 >> 8, k = r2 & 255;
    val = W2[i * 32768 + k * 128 + n];
  }
  wt[idx] = (f16)val;
}

// ---------------- Flash attention, S^T-layout (register-resident P) -------
__global__ __launch_bounds__(256) void attn_kernel(
    const f16* __restrict__ qh, const f16* __restrict__ kh,
    const f16* __restrict__ vth, const float* __restrict__ mask,
    f16* __restrict__ o) {
  __shared__ f16 Ks[2][64][40];
  __shared__ f16 Vt[2][32][72];
  __shared__ float mks[2][64];
  const int t = threadIdx.x;
  const int wave = t >> 6, lane = t & 63;
  const int g = lane >> 4, c = lane & 15;
  const int bh = blockIdx.y;
  const int b = bh >> 2;
  const int qw = blockIdx.x * 128 + wave * 32;

  f16x8 qfrag[2];
  float mqv[2];
#pragma unroll
  for (int qt = 0; qt < 2; ++qt) {
    qfrag[qt] =
        *(const f16x8*)(qh + ((size_t)bh * LL + qw + qt * 16 + c) * DKK + g * 8);
    mqv[qt] = mask[b * LL + qw + qt * 16 + c];
  }

  f32x4 o4[2][2];
  float m[2], l[2];
#pragma unroll
  for (int qt = 0; qt < 2; ++qt) {
    m[qt] = -3.0e38f; l[qt] = 0.f;
#pragma unroll
    for (int dt = 0; dt < 2; ++dt)
#pragma unroll
      for (int r = 0; r < 4; ++r) o4[qt][dt][r] = 0.f;
  }

  const f16* kbase = kh + (size_t)bh * LL * DKK;
  const f16* vbase = vth + (size_t)bh * DKK * LL;
  const int krow = t >> 2, kch = t & 3;
  const int vd = t >> 3, vseg = t & 7;

  f16x8 kreg = *(const f16x8*)(kbase + (size_t)krow * DKK + kch * 8);
  f16x8 vreg = *(const f16x8*)(vbase + (size_t)vd * LL + vseg * 8);
  float mreg = (t < 64) ? mask[b * LL + t] : 0.f;
  *(f16x8*)&Ks[0][krow][kch * 8] = kreg;
  *(f16x8*)&Vt[0][vd][vseg * 8] = vreg;
  if (t < 64) mks[0][t] = mreg;
  __syncthreads();

  for (int kt = 0; kt < LL / 64; ++kt) {
    const int cur = kt & 1;
    if (kt < LL / 64 - 1) {
      const int k0 = (kt + 1) * 64;
      kreg = *(const f16x8*)(kbase + (size_t)(k0 + krow) * DKK + kch * 8);
      vreg = *(const f16x8*)(vbase + (size_t)vd * LL + k0 + vseg * 8);
      if (t < 64) mreg = mask[b * LL + k0 + t];
    }

    f16x8 kb[4];
#pragma unroll
    for (int nt = 0; nt < 4; ++nt)
      kb[nt] = *(const f16x8*)&Ks[cur][nt * 16 + c][g * 8];
    f32x4 st[2][4];
#pragma unroll
    for (int qt = 0; qt < 2; ++qt)
#pragma unroll
      for (int nt = 0; nt < 4; ++nt) {
        f32x4 z = {0.f, 0.f, 0.f, 0.f};
        st[qt][nt] =
            __builtin_amdgcn_mfma_f32_16x16x32_f16(kb[nt], qfrag[qt], z, 0, 0, 0);
      }

    float4 mk4[4];
#pragma unroll
    for (int nt = 0; nt < 4; ++nt)
      mk4[nt] = *(const float4*)&mks[cur][nt * 16 + 4 * g];
#pragma unroll
    for (int qt = 0; qt < 2; ++qt) {
      const float mq = mqv[qt];
#pragma unroll
      for (int nt = 0; nt < 4; ++nt) {
        st[qt][nt][0] += (1.f - mq * mk4[nt].x) * NEGMIN;
        st[qt][nt][1] += (1.f - mq * mk4[nt].y) * NEGMIN;
        st[qt][nt][2] += (1.f - mq * mk4[nt].z) * NEGMIN;
        st[qt][nt][3] += (1.f - mq * mk4[nt].w) * NEGMIN;
      }
    }

    f16x4 va[2][4];
#pragma unroll
    for (int dt = 0; dt < 2; ++dt)
#pragma unroll
      for (int nt = 0; nt < 4; ++nt)
        va[dt][nt] = *(const f16x4*)&Vt[cur][dt * 16 + c][nt * 16 + 4 * g];

#pragma unroll
    for (int qt = 0; qt < 2; ++qt) {
      float mx01 = fmaxf(fmaxf(st[qt][0][0], st[qt][0][1]),
                         fmaxf(st[qt][0][2], st[qt][0][3]));
      float mx23 = fmaxf(fmaxf(st[qt][1][0], st[qt][1][1]),
                         fmaxf(st[qt][1][2], st[qt][1][3]));
      float mx45 = fmaxf(fmaxf(st[qt][2][0], st[qt][2][1]),
                         fmaxf(st[qt][2][2], st[qt][2][3]));
      float mx67 = fmaxf(fmaxf(st[qt][3][0], st[qt][3][1]),
                         fmaxf(st[qt][3][2], st[qt][3][3]));
      float vmax = fmaxf(fmaxf(mx01, mx23), fmaxf(mx45, mx67));
      vmax = fmaxf(vmax, __shfl_xor(vmax, 16));
      vmax = fmaxf(vmax, __shfl_xor(vmax, 32));
      const float mn = fmaxf(m[qt], vmax);
      const float sc = __builtin_exp2f((m[qt] - mn) * LOG2E);
      const float mn2 = mn * LOG2E;
      m[qt] = mn;

      float p[4][4];
      float psum = 0.f;
#pragma unroll
      for (int nt = 0; nt < 4; ++nt) {
        float s0 = 0.f;
#pragma unroll
        for (int r = 0; r < 4; ++r) {
          p[nt][r] = __builtin_exp2f(fmaf(st[qt][nt][r], LOG2E, -mn2));
          s0 += p[nt][r];
        }
        psum += s0;
      }
      psum += __shfl_xor(psum, 16);
      psum += __shfl_xor(psum, 32);
      l[qt] = l[qt] * sc + psum;

#pragma unroll
      for (int dt = 0; dt < 2; ++dt)
#pragma unroll
        for (int r = 0; r < 4; ++r) o4[qt][dt][r] *= sc;

#pragma unroll
      for (int nt = 0; nt < 4; ++nt) {
        f16x4 pk;
        pk[0] = (f16)p[nt][0];
        pk[1] = (f16)p[nt][1];
        pk[2] = (f16)p[nt][2];
        pk[3] = (f16)p[nt][3];
#pragma unroll
        for (int dt = 0; dt < 2; ++dt)
          o4[qt][dt] = __builtin_amdgcn_mfma_f32_16x16x16f16(
              va[dt][nt], pk, o4[qt][dt], 0, 0, 0);
      }
    }

    if (kt < LL / 64 - 1) {
      *(f16x8*)&Ks[1 - cur][krow][kch * 8] = kreg;
      *(f16x8*)&Vt[1 - cur][vd][vseg * 8] = vreg;
      if (t < 64) mks[1 - cur][t] = mreg;
    }
    __syncthreads();
  }

  // epilogue: write f16 o
  const int h = bh & 3;
#pragma unroll
  for (int qt = 0; qt < 2; ++qt) {
    const float rdiv = 1.f / l[qt];
    f16* orow = o + ((size_t)b * LL + qw + qt * 16 + c) * DD + h * DKK;
#pragma unroll
    for (int dt = 0; dt < 2; ++dt) {
      f16x4 res;
      res[0] = (f16)(o4[qt][dt][0] * rdiv);
      res[1] = (f16)(o4[qt][dt][1] * rdiv);
      res[2] = (f16)(o4[qt][dt][2] * rdiv);
      res[3] = (f16)(o4[qt][dt][3] * rdiv);
      *(f16x4*)(orow + dt * 16 + g * 4) = res;
    }
  }
}

// ---------------- MFMA MLP: oproj+res -> FFN1+gelu -> FFN2+res ------------
// 64 rows/block, 256 threads, 4 waves; wave owns one 16-row m-tile
// end-to-end (all LDS traffic wave-local -> no barriers).
__global__ __launch_bounds__(256) void mlp_kernel(
    const f16* __restrict__ o, const float* __restrict__ x,
    const f16* __restrict__ WoT, const f16* __restrict__ W1T,
    const f16* __restrict__ W2T, const float* __restrict__ b1,
    const float* __restrict__ b2, float* __restrict__ xout) {
  __shared__ f16 Xm[64][136];
  __shared__ f16 Fs[64][264];
  const int t = threadIdx.x;
  const int wave = t >> 6, lane = t & 63;
  const int g = lane >> 4, c = lane & 15;
  const int mrow = wave * 16;
  const long r0 = (long)blockIdx.x * 64;

  // ---- step1: xm = (o @ Wo + x) * 0.5 ----
  f16x8 a1[4];
#pragma unroll
  for (int kt = 0; kt < 4; ++kt)
    a1[kt] = *(const f16x8*)(o + (r0 + mrow + c) * 128 + kt * 32 + g * 8);

  f32x4 xmreg[8];
#pragma unroll
  for (int nt = 0; nt < 8; ++nt) {
    f32x4 acc = {0.f, 0.f, 0.f, 0.f};
#pragma unroll
    for (int kt = 0; kt < 4; ++kt) {
      f16x8 bfrag = *(const f16x8*)(WoT + (nt * 16 + c) * 128 + kt * 32 + g * 8);
      acc = __builtin_amdgcn_mfma_f32_16x16x32_f16(a1[kt], bfrag, acc, 0, 0, 0);
    }
#pragma unroll
    for (int r = 0; r < 4; ++r) {
      const float xv = x[(r0 + mrow + 4 * g + r) * 128 + nt * 16 + c];
      acc[r] = (acc[r] + xv) * 0.5f;
      Xm[mrow + 4 * g + r][nt * 16 + c] = (f16)acc[r];
    }
    xmreg[nt] = acc;
  }

  // ---- step2: f = gelu(xm @ W1 + b1) ----
  f16x8 a2[4];
#pragma unroll
  for (int kt = 0; kt < 4; ++kt)
    a2[kt] = *(const f16x8*)&Xm[mrow + c][kt * 32 + g * 8];
#pragma unroll
  for (int nt = 0; nt < 16; ++nt) {
    f32x4 acc = {0.f, 0.f, 0.f, 0.f};
#pragma unroll
    for (int kt = 0; kt < 4; ++kt) {
      f16x8 bfrag = *(const f16x8*)(W1T + (nt * 16 + c) * 128 + kt * 32 + g * 8);
      acc = __builtin_amdgcn_mfma_f32_16x16x32_f16(a2[kt], bfrag, acc, 0, 0, 0);
    }
    const float bj = b1[nt * 16 + c];
#pragma unroll
    for (int r = 0; r < 4; ++r) {
      const float val = acc[r] + bj;
      Fs[mrow + 4 * g + r][nt * 16 + c] =
          (f16)(0.5f * val * (1.f + erff(val * 0.70710678118654752f)));
    }
  }

  // ---- step3: out = (f @ W2 + b2 + xm) * 0.5 ----
  f16x8 a3[8];
#pragma unroll
  for (int kt = 0; kt < 8; ++kt)
    a3[kt] = *(const f16x8*)&Fs[mrow + c][kt * 32 + g * 8];
#pragma unroll
  for (int nt = 0; nt < 8; ++nt) {
    f32x4 acc = {0.f, 0.f, 0.f, 0.f};
#pragma unroll
    for (int kt = 0; kt < 8; ++kt) {
      f16x8 bfrag = *(const f16x8*)(W2T + (nt * 16 + c) * 256 + kt * 32 + g * 8);
      acc = __builtin_amdgcn_mfma_f32_16x16x32_f16(a3[kt], bfrag, acc, 0, 0, 0);
    }
    const float bj = b2[nt * 16 + c];
#pragma unroll
    for (int r = 0; r < 4; ++r)
      xout[(r0 + mrow + 4 * g + r) * 128 + nt * 16 + c] =
          (acc[r] + bj + xmreg[nt][r]) * 0.5f;
  }
}

extern "C" void kernel_launch(void* const* d_in, const int* in_sizes, int n_in,
                              void* d_out, int out_size, void* d_ws,
                              size_t ws_size, hipStream_t stream) {
  const float* x    = (const float*)d_in[0];
  const float* mask = (const float*)d_in[1];
  const float* Wq   = (const float*)d_in[2];
  const float* Wk   = (const float*)d_in[3];
  const float* Wv   = (const float*)d_in[4];
  const float* Wo   = (const float*)d_in[5];
  const float* W1   = (const float*)d_in[6];
  const float* b1   = (const float*)d_in[7];
  const float* W2   = (const float*)d_in[8];
  const float* b2   = (const float*)d_in[9];

  const size_t SZ = (size_t)BB * LL * DD;
  char* p = (char*)d_ws;
  f16* qh   = (f16*)p;  p += SZ * sizeof(f16);
  f16* kh   = (f16*)p;  p += SZ * sizeof(f16);
  f16* vth  = (f16*)p;  p += SZ * sizeof(f16);
  f16* ob   = (f16*)p;  p += SZ * sizeof(f16);
  f16* wt   = (f16*)p;  p += (size_t)2 * 81920 * sizeof(f16);
  float* xA = (float*)p;

  const int rowBlocks = (BB * LL) / 16;   // 1024

  // one-time weight transpose+convert (both layers)
  wconv_kernel<<<640, 256, 0, stream>>>(Wo, W1, W2, wt);

  for (int i = 0; i < 2; ++i) {
    const float* xin = (i == 0) ? x : xA;
    float* xout = (i == 1) ? (float*)d_out : xA;
    const float* Wq_i = Wq + (long)i * HH * DD * DKK;
    const float* Wk_i = Wk + (long)i * HH * DD * DKK;
    const float* Wv_i = Wv + (long)i * HH * DD * DKK;
    const f16* WoT_i = wt + (size_t)i * 81920;
    const f16* W1T_i = wt + (size_t)i * 81920 + 16384;
    const f16* W2T_i = wt + (size_t)i * 81920 + 49152;
    const float* b1_i = b1 + (long)i * DFFF;
    const float* b2_i = b2 + (long)i * DD;

    qkv_kernel<<<rowBlocks, 384, 0, stream>>>(xin, Wq_i, Wk_i, Wv_i, qh, kh, vth);
    attn_kernel<<<dim3(LL / 128, BB * HH), 256, 0, stream>>>(qh, kh, vth, mask, ob);
    mlp_kernel<<<(BB * LL) / 64, 256, 0, stream>>>(ob, xin, WoT_i, W1T_i, W2T_i,
                                                   b1_i, b2_i, xout);
  }
}

// Round 7
// 273.212 us; speedup vs baseline: 1.5944x; 1.0111x over previous
//
#include <hip/hip_runtime.h>
#include <math.h>

#define BB 8
#define LL 2048
#define DD 128
#define HH 4
#define DKK 32
#define DFFF 256

#define NEGMIN (-3.402823466e38f)
#define LOG2E 1.44269504088896f

typedef _Float16 f16;
typedef _Float16 f16x4 __attribute__((ext_vector_type(4)));
typedef _Float16 f16x8 __attribute__((ext_vector_type(8)));
typedef __fp16 h16x2 __attribute__((ext_vector_type(2)));
typedef float f32x4 __attribute__((ext_vector_type(4)));

union PKU { h16x2 h2[2]; f16x4 v; };

// ---------------- x -> f16 convert ----------------
__global__ __launch_bounds__(256) void xcvt_kernel(const float* __restrict__ x,
                                                   f16* __restrict__ xh) {
  const int i = (blockIdx.x * 256 + threadIdx.x) * 8;
  float4 v0 = *(const float4*)(x + i);
  float4 v1 = *(const float4*)(x + i + 4);
  f16x8 h;
  h[0] = (f16)v0.x; h[1] = (f16)v0.y; h[2] = (f16)v0.z; h[3] = (f16)v0.w;
  h[4] = (f16)v1.x; h[5] = (f16)v1.y; h[6] = (f16)v1.z; h[7] = (f16)v1.w;
  *(f16x8*)(xh + i) = h;
}

// ---------------- weight convert: all weights -> f16 transposed [n][k] ----
// layer stride 131072: [0,49152) qkvT (sel*16384 + n*128 + k),
// [49152,65536) WoT, [65536,98304) W1T, [98304,131072) W2T
__global__ __launch_bounds__(256) void wconv_kernel(
    const float* __restrict__ Wq, const float* __restrict__ Wk,
    const float* __restrict__ Wv, const float* __restrict__ Wo,
    const float* __restrict__ W1, const float* __restrict__ W2,
    f16* __restrict__ wt) {
  const int idx = blockIdx.x * 256 + threadIdx.x;
  const int i = idx >> 17;
  const int r = idx & 131071;
  float val;
  if (r < 49152) {
    const int sel = r / 16384;
    const int rr = r & 16383;
    const int n = rr >> 7, k = rr & 127;
    const float* W = (sel == 0) ? Wq : (sel == 1) ? Wk : Wv;
    val = W[((size_t)(i * 4 + (n >> 5)) * 128 + k) * 32 + (n & 31)];
  } else if (r < 65536) {
    const int r2 = r - 49152;
    const int n = r2 >> 7, k = r2 & 127;
    val = Wo[i * 16384 + k * 128 + n];
  } else if (r < 98304) {
    const int r2 = r - 65536;
    const int n = r2 >> 7, k = r2 & 127;
    val = W1[i * 32768 + k * 256 + n];
  } else {
    const int r2 = r - 98304;
    const int n = r2 >> 8, k = r2 & 255;
    val = W2[i * 32768 + k * 128 + n];
  }
  wt[idx] = (f16)val;
}

// ---------------- QKV projection via MFMA ----------------
// grid M/64 = 256 blocks, 4 waves; wave owns 16 rows.
__global__ __launch_bounds__(256) void qkv_kernel(
    const f16* __restrict__ xh, const f16* __restrict__ wqkvT,
    f16* __restrict__ qh, f16* __restrict__ kh, f16* __restrict__ vth) {
  const int t = threadIdx.x;
  const int wave = t >> 6, lane = t & 63;
  const int g = lane >> 4, c = lane & 15;
  const int r0g = blockIdx.x * 64 + wave * 16;
  const int b4 = (r0g >> 11) * 4;
  const int l0 = r0g & 2047;

  f16x8 a[4];
#pragma unroll
  for (int kt = 0; kt < 4; ++kt)
    a[kt] = *(const f16x8*)(xh + (size_t)(r0g + c) * 128 + kt * 32 + g * 8);

  // ---- q and k: C[m=l][n] ----
#pragma unroll
  for (int sel = 0; sel < 2; ++sel) {
    const f16* wT = wqkvT + sel * 16384;
    f16* out = (sel == 0) ? qh : kh;
#pragma unroll
    for (int nt = 0; nt < 8; ++nt) {
      f32x4 acc = {0.f, 0.f, 0.f, 0.f};
#pragma unroll
      for (int kt = 0; kt < 4; ++kt) {
        f16x8 bfrag = *(const f16x8*)(wT + (nt * 16 + c) * 128 + kt * 32 + g * 8);
        acc = __builtin_amdgcn_mfma_f32_16x16x32_f16(a[kt], bfrag, acc, 0, 0, 0);
      }
      const int h = nt >> 1, e = (nt & 1) * 16 + c;
#pragma unroll
      for (int r = 0; r < 4; ++r) {
        const int l = l0 + 4 * g + r;
        out[((size_t)(b4 + h) * LL + l) * DKK + e] = (f16)acc[r];
      }
    }
  }

  // ---- v transposed: swapped operands -> C[e_glob][l] ----
  {
    const f16* wT = wqkvT + 2 * 16384;
#pragma unroll
    for (int nt = 0; nt < 8; ++nt) {
      f32x4 acc = {0.f, 0.f, 0.f, 0.f};
#pragma unroll
      for (int kt = 0; kt < 4; ++kt) {
        f16x8 afrag = *(const f16x8*)(wT + (nt * 16 + c) * 128 + kt * 32 + g * 8);
        acc = __builtin_amdgcn_mfma_f32_16x16x32_f16(afrag, a[kt], acc, 0, 0, 0);
      }
#pragma unroll
      for (int r = 0; r < 4; ++r) {
        const int eg = nt * 16 + 4 * g + r;
        vth[((size_t)(b4 + (eg >> 5)) * DKK + (eg & 31)) * LL + l0 + c] =
            (f16)acc[r];
      }
    }
  }
}

// ---------------- Flash attention, KVB=128, mask-skip, defer-max ----------
#define KVB 128
#define NT (LL / KVB)
__global__ __launch_bounds__(256) void attn_kernel(
    const f16* __restrict__ qh, const f16* __restrict__ kh,
    const f16* __restrict__ vth, const float* __restrict__ mask,
    f16* __restrict__ o) {
  __shared__ f16 Ks[2][KVB][40];
  __shared__ f16 Vt[2][32][KVB + 8];
  __shared__ float mks[2][KVB];
  __shared__ int mkflag[2][4];
  const int t = threadIdx.x;
  const int wave = t >> 6, lane = t & 63;
  const int g = lane >> 4, c = lane & 15;

  // XCD-aware remap: all 16 q-blocks of one bh land on one XCD
  const int flat = blockIdx.y * 16 + blockIdx.x;
  const int xcd = flat & 7, slot = flat >> 3;
  const int bh = xcd * 4 + (slot >> 4);
  const int qb = slot & 15;
  const int b = bh >> 2;
  const int qw = qb * 128 + wave * 32;

  f16x8 qfrag[2];
  float mqv[2];
#pragma unroll
  for (int qt = 0; qt < 2; ++qt) {
    qfrag[qt] =
        *(const f16x8*)(qh + ((size_t)bh * LL + qw + qt * 16 + c) * DKK + g * 8);
    mqv[qt] = mask[b * LL + qw + qt * 16 + c];
  }
  const bool qflag = __all(mqv[0] == 1.f && mqv[1] == 1.f);

  f32x4 o4[2][2];
  float m[2], l[2];
#pragma unroll
  for (int qt = 0; qt < 2; ++qt) {
    m[qt] = -3.0e38f; l[qt] = 0.f;
#pragma unroll
    for (int dt = 0; dt < 2; ++dt)
#pragma unroll
      for (int r = 0; r < 4; ++r) o4[qt][dt][r] = 0.f;
  }

  const f16* kbase = kh + (size_t)bh * LL * DKK;
  const f16* vbase = vth + (size_t)bh * DKK * LL;
  const int krow = t >> 1, kco = (t & 1) * 16;   // 128 rows x 2 chunks of 16
  const int vd = t >> 3, vco = (t & 7) * 16;     // 32 d-rows x 8 segs of 16

  // prologue: stage tile 0
  f16x8 kr0 = *(const f16x8*)(kbase + (size_t)krow * DKK + kco);
  f16x8 kr1 = *(const f16x8*)(kbase + (size_t)krow * DKK + kco + 8);
  f16x8 vr0 = *(const f16x8*)(vbase + (size_t)vd * LL + vco);
  f16x8 vr1 = *(const f16x8*)(vbase + (size_t)vd * LL + vco + 8);
  float mreg = (t < KVB) ? mask[b * LL + t] : 1.f;
  *(f16x8*)&Ks[0][krow][kco] = kr0;
  *(f16x8*)&Ks[0][krow][kco + 8] = kr1;
  *(f16x8*)&Vt[0][vd][vco] = vr0;
  *(f16x8*)&Vt[0][vd][vco + 8] = vr1;
  if (t < KVB) mks[0][t] = mreg;
  {
    unsigned long long ok = __ballot(mreg == 1.f);
    if (lane == 0) mkflag[0][wave] = (ok == ~0ull);
  }
  __syncthreads();

  for (int kt = 0; kt < NT; ++kt) {
    const int cur = kt & 1;
    if (kt < NT - 1) {   // issue next tile's loads early
      const int k0 = (kt + 1) * KVB;
      kr0 = *(const f16x8*)(kbase + (size_t)(k0 + krow) * DKK + kco);
      kr1 = *(const f16x8*)(kbase + (size_t)(k0 + krow) * DKK + kco + 8);
      vr0 = *(const f16x8*)(vbase + (size_t)vd * LL + k0 + vco);
      vr1 = *(const f16x8*)(vbase + (size_t)vd * LL + k0 + vco + 8);
      mreg = (t < KVB) ? mask[b * LL + k0 + t] : 1.f;
    }

    const bool nomask = qflag && mkflag[cur][0] && mkflag[cur][1];

    // ---- fragment loads ----
    f16x8 kb[8];
#pragma unroll
    for (int nt = 0; nt < 8; ++nt)
      kb[nt] = *(const f16x8*)&Ks[cur][nt * 16 + c][g * 8];
    f16x4 va[2][8];
#pragma unroll
    for (int dt = 0; dt < 2; ++dt)
#pragma unroll
      for (int nt = 0; nt < 8; ++nt)
        va[dt][nt] = *(const f16x4*)&Vt[cur][dt * 16 + c][nt * 16 + 4 * g];

#pragma unroll
    for (int qt = 0; qt < 2; ++qt) {
      // ---- QK^T: S^T[kv=16nt+4g+r][q=c] ----
      f32x4 st[8];
      __builtin_amdgcn_s_setprio(1);
#pragma unroll
      for (int nt = 0; nt < 8; ++nt) {
        f32x4 z = {0.f, 0.f, 0.f, 0.f};
        st[nt] =
            __builtin_amdgcn_mfma_f32_16x16x32_f16(kb[nt], qfrag[qt], z, 0, 0, 0);
      }
      __builtin_amdgcn_s_setprio(0);

      if (!nomask) {
        const float mq = mqv[qt];
#pragma unroll
        for (int nt = 0; nt < 8; ++nt) {
          float4 mk4 = *(const float4*)&mks[cur][nt * 16 + 4 * g];
          st[nt][0] += (1.f - mq * mk4.x) * NEGMIN;
          st[nt][1] += (1.f - mq * mk4.y) * NEGMIN;
          st[nt][2] += (1.f - mq * mk4.z) * NEGMIN;
          st[nt][3] += (1.f - mq * mk4.w) * NEGMIN;
        }
      }

      // ---- row max (31 fmax + 2 shfl) ----
      float vmax = fmaxf(fmaxf(st[0][0], st[0][1]), fmaxf(st[0][2], st[0][3]));
#pragma unroll
      for (int nt = 1; nt < 8; ++nt) {
        float mx = fmaxf(fmaxf(st[nt][0], st[nt][1]),
                         fmaxf(st[nt][2], st[nt][3]));
        vmax = fmaxf(vmax, mx);
      }
      vmax = fmaxf(vmax, __shfl_xor(vmax, 16));
      vmax = fmaxf(vmax, __shfl_xor(vmax, 32));

      // defer-max: skip rescale while growth <= 8
      if (!__all(vmax - m[qt] <= 8.f)) {
        const float mn = fmaxf(m[qt], vmax);
        const float sc = __builtin_exp2f((m[qt] - mn) * LOG2E);
        l[qt] *= sc;
#pragma unroll
        for (int dt = 0; dt < 2; ++dt)
#pragma unroll
          for (int r = 0; r < 4; ++r) o4[qt][dt][r] *= sc;
        m[qt] = mn;
      }
      const float mn2 = m[qt] * LOG2E;

      float p[8][4];
      float psum = 0.f;
#pragma unroll
      for (int nt = 0; nt < 8; ++nt) {
        float s0 = 0.f;
#pragma unroll
        for (int r = 0; r < 4; ++r) {
          p[nt][r] = __builtin_exp2f(fmaf(st[nt][r], LOG2E, -mn2));
          s0 += p[nt][r];
        }
        psum += s0;
      }
      psum += __shfl_xor(psum, 16);
      psum += __shfl_xor(psum, 32);
      l[qt] += psum;

      // ---- pack P + PV ----
      __builtin_amdgcn_s_setprio(1);
#pragma unroll
      for (int nt = 0; nt < 8; ++nt) {
        PKU pk;
        pk.h2[0] = __builtin_amdgcn_cvt_pkrtz(p[nt][0], p[nt][1]);
        pk.h2[1] = __builtin_amdgcn_cvt_pkrtz(p[nt][2], p[nt][3]);
        o4[qt][0] = __builtin_amdgcn_mfma_f32_16x16x16f16(va[0][nt], pk.v,
                                                          o4[qt][0], 0, 0, 0);
        o4[qt][1] = __builtin_amdgcn_mfma_f32_16x16x16f16(va[1][nt], pk.v,
                                                          o4[qt][1], 0, 0, 0);
      }
      __builtin_amdgcn_s_setprio(0);
    }

    // commit next tile
    if (kt < NT - 1) {
      *(f16x8*)&Ks[1 - cur][krow][kco] = kr0;
      *(f16x8*)&Ks[1 - cur][krow][kco + 8] = kr1;
      *(f16x8*)&Vt[1 - cur][vd][vco] = vr0;
      *(f16x8*)&Vt[1 - cur][vd][vco + 8] = vr1;
      if (t < KVB) mks[1 - cur][t] = mreg;
      unsigned long long ok = __ballot(mreg == 1.f);
      if (lane == 0) mkflag[1 - cur][wave] = (ok == ~0ull);
    }
    __syncthreads();
  }

  // ---- epilogue ----
  const int h = bh & 3;
#pragma unroll
  for (int qt = 0; qt < 2; ++qt) {
    const float rdiv = 1.f / l[qt];
    f16* orow = o + ((size_t)b * LL + qw + qt * 16 + c) * DD + h * DKK;
#pragma unroll
    for (int dt = 0; dt < 2; ++dt) {
      f16x4 res;
      res[0] = (f16)(o4[qt][dt][0] * rdiv);
      res[1] = (f16)(o4[qt][dt][1] * rdiv);
      res[2] = (f16)(o4[qt][dt][2] * rdiv);
      res[3] = (f16)(o4[qt][dt][3] * rdiv);
      *(f16x4*)(orow + dt * 16 + g * 4) = res;
    }
  }
}

// ---------------- MFMA MLP: oproj+res -> FFN1+gelu -> FFN2+res ------------
__global__ __launch_bounds__(256) void mlp_kernel(
    const f16* __restrict__ o, const float* __restrict__ x,
    const f16* __restrict__ WoT, const f16* __restrict__ W1T,
    const f16* __restrict__ W2T, const float* __restrict__ b1,
    const float* __restrict__ b2, float* __restrict__ xout,
    f16* __restrict__ xhout) {
  __shared__ f16 Xm[64][136];
  __shared__ f16 Fs[64][264];
  const int t = threadIdx.x;
  const int wave = t >> 6, lane = t & 63;
  const int g = lane >> 4, c = lane & 15;
  const int mrow = wave * 16;
  const long r0 = (long)blockIdx.x * 64;

  // ---- step1: xm = (o @ Wo + x) * 0.5 ----
  f16x8 a1[4];
#pragma unroll
  for (int kt = 0; kt < 4; ++kt)
    a1[kt] = *(const f16x8*)(o + (r0 + mrow + c) * 128 + kt * 32 + g * 8);

  f32x4 xmreg[8];
#pragma unroll
  for (int nt = 0; nt < 8; ++nt) {
    f32x4 acc = {0.f, 0.f, 0.f, 0.f};
#pragma unroll
    for (int kt = 0; kt < 4; ++kt) {
      f16x8 bfrag = *(const f16x8*)(WoT + (nt * 16 + c) * 128 + kt * 32 + g * 8);
      acc = __builtin_amdgcn_mfma_f32_16x16x32_f16(a1[kt], bfrag, acc, 0, 0, 0);
    }
#pragma unroll
    for (int r = 0; r < 4; ++r) {
      const float xv = x[(r0 + mrow + 4 * g + r) * 128 + nt * 16 + c];
      acc[r] = (acc[r] + xv) * 0.5f;
      Xm[mrow + 4 * g + r][nt * 16 + c] = (f16)acc[r];
    }
    xmreg[nt] = acc;
  }

  // ---- step2: f = gelu(xm @ W1 + b1) ----
  f16x8 a2[4];
#pragma unroll
  for (int kt = 0; kt < 4; ++kt)
    a2[kt] = *(const f16x8*)&Xm[mrow + c][kt * 32 + g * 8];
#pragma unroll
  for (int nt = 0; nt < 16; ++nt) {
    f32x4 acc = {0.f, 0.f, 0.f, 0.f};
#pragma unroll
    for (int kt = 0; kt < 4; ++kt) {
      f16x8 bfrag = *(const f16x8*)(W1T + (nt * 16 + c) * 128 + kt * 32 + g * 8);
      acc = __builtin_amdgcn_mfma_f32_16x16x32_f16(a2[kt], bfrag, acc, 0, 0, 0);
    }
    const float bj = b1[nt * 16 + c];
#pragma unroll
    for (int r = 0; r < 4; ++r) {
      const float val = acc[r] + bj;
      Fs[mrow + 4 * g + r][nt * 16 + c] =
          (f16)(0.5f * val * (1.f + erff(val * 0.70710678118654752f)));
    }
  }

  // ---- step3: out = (f @ W2 + b2 + xm) * 0.5 ----
  f16x8 a3[8];
#pragma unroll
  for (int kt = 0; kt < 8; ++kt)
    a3[kt] = *(const f16x8*)&Fs[mrow + c][kt * 32 + g * 8];
#pragma unroll
  for (int nt = 0; nt < 8; ++nt) {
    f32x4 acc = {0.f, 0.f, 0.f, 0.f};
#pragma unroll
    for (int kt = 0; kt < 8; ++kt) {
      f16x8 bfrag = *(const f16x8*)(W2T + (nt * 16 + c) * 256 + kt * 32 + g * 8);
      acc = __builtin_amdgcn_mfma_f32_16x16x32_f16(a3[kt], bfrag, acc, 0, 0, 0);
    }
    const float bj = b2[nt * 16 + c];
#pragma unroll
    for (int r = 0; r < 4; ++r) {
      const float val = (acc[r] + bj + xmreg[nt][r]) * 0.5f;
      xout[(r0 + mrow + 4 * g + r) * 128 + nt * 16 + c] = val;
      xhout[(r0 + mrow + 4 * g + r) * 128 + nt * 16 + c] = (f16)val;
    }
  }
}

extern "C" void kernel_launch(void* const* d_in, const int* in_sizes, int n_in,
                              void* d_out, int out_size, void* d_ws,
                              size_t ws_size, hipStream_t stream) {
  const float* x    = (const float*)d_in[0];
  const float* mask = (const float*)d_in[1];
  const float* Wq   = (const float*)d_in[2];
  const float* Wk   = (const float*)d_in[3];
  const float* Wv   = (const float*)d_in[4];
  const float* Wo   = (const float*)d_in[5];
  const float* W1   = (const float*)d_in[6];
  const float* b1   = (const float*)d_in[7];
  const float* W2   = (const float*)d_in[8];
  const float* b2   = (const float*)d_in[9];

  const size_t SZ = (size_t)BB * LL * DD;   // 2,097,152
  char* p = (char*)d_ws;
  f16* qh   = (f16*)p;  p += SZ * sizeof(f16);
  f16* kh   = (f16*)p;  p += SZ * sizeof(f16);
  f16* vth  = (f16*)p;  p += SZ * sizeof(f16);
  f16* ob   = (f16*)p;  p += SZ * sizeof(f16);
  f16* xh0  = (f16*)p;  p += SZ * sizeof(f16);
  f16* xh1  = (f16*)p;  p += SZ * sizeof(f16);
  f16* wt   = (f16*)p;  p += (size_t)262144 * sizeof(f16);
  float* xA = (float*)p;

  // one-time converts
  wconv_kernel<<<1024, 256, 0, stream>>>(Wq, Wk, Wv, Wo, W1, W2, wt);
  xcvt_kernel<<<SZ / 8 / 256, 256, 0, stream>>>(x, xh0);

  for (int i = 0; i < 2; ++i) {
    const float* xin = (i == 0) ? x : xA;
    const f16* xhin = (i == 0) ? xh0 : xh1;
    float* xout = (i == 1) ? (float*)d_out : xA;
    f16* xhout = (i == 0) ? xh1 : xh0;   // layer1's f16 out unused; reuse xh0
    const f16* qkvT_i = wt + (size_t)i * 131072;
    const f16* WoT_i  = wt + (size_t)i * 131072 + 49152;
    const f16* W1T_i  = wt + (size_t)i * 131072 + 65536;
    const f16* W2T_i  = wt + (size_t)i * 131072 + 98304;
    const float* b1_i = b1 + (long)i * DFFF;
    const float* b2_i = b2 + (long)i * DD;

    qkv_kernel<<<(BB * LL) / 64, 256, 0, stream>>>(xhin, qkvT_i, qh, kh, vth);
    attn_kernel<<<dim3(LL / 128, BB * HH), 256, 0, stream>>>(qh, kh, vth, mask, ob);
    mlp_kernel<<<(BB * LL) / 64, 256, 0, stream>>>(ob, xin, WoT_i, W1T_i, W2T_i,
                                                   b1_i, b2_i, xout, xhout);
  }
}

// Round 8
// 218.471 us; speedup vs baseline: 1.9939x; 1.2506x over previous
//
#include <hip/hip_runtime.h>
#include <math.h>

#define BB 8
#define LL 2048
#define DD 128
#define HH 4
#define DKK 32
#define DFFF 256

#define NEGMIN (-3.402823466e38f)
#define LOG2E 1.44269504088896f

typedef _Float16 f16;
typedef _Float16 f16x4 __attribute__((ext_vector_type(4)));
typedef _Float16 f16x8 __attribute__((ext_vector_type(8)));
typedef __fp16 h16x2 __attribute__((ext_vector_type(2)));
typedef float f32x4 __attribute__((ext_vector_type(4)));

union PKU { h16x2 h2[2]; f16x4 v; };

// ---------------- x -> f16 convert ----------------
__global__ __launch_bounds__(256) void xcvt_kernel(const float* __restrict__ x,
                                                   f16* __restrict__ xh) {
  const int i = (blockIdx.x * 256 + threadIdx.x) * 8;
  float4 v0 = *(const float4*)(x + i);
  float4 v1 = *(const float4*)(x + i + 4);
  f16x8 h;
  h[0] = (f16)v0.x; h[1] = (f16)v0.y; h[2] = (f16)v0.z; h[3] = (f16)v0.w;
  h[4] = (f16)v1.x; h[5] = (f16)v1.y; h[6] = (f16)v1.z; h[7] = (f16)v1.w;
  *(f16x8*)(xh + i) = h;
}

// ---------------- weight convert: all weights -> f16 transposed [n][k] ----
// layer stride 131072: [0,49152) qkvT (sel*16384 + n*128 + k),
// [49152,65536) WoT, [65536,98304) W1T, [98304,131072) W2T
__global__ __launch_bounds__(256) void wconv_kernel(
    const float* __restrict__ Wq, const float* __restrict__ Wk,
    const float* __restrict__ Wv, const float* __restrict__ Wo,
    const float* __restrict__ W1, const float* __restrict__ W2,
    f16* __restrict__ wt) {
  const int idx = blockIdx.x * 256 + threadIdx.x;
  const int i = idx >> 17;
  const int r = idx & 131071;
  float val;
  if (r < 49152) {
    const int sel = r / 16384;
    const int rr = r & 16383;
    const int n = rr >> 7, k = rr & 127;
    const float* W = (sel == 0) ? Wq : (sel == 1) ? Wk : Wv;
    val = W[((size_t)(i * 4 + (n >> 5)) * 128 + k) * 32 + (n & 31)];
  } else if (r < 65536) {
    const int r2 = r - 49152;
    const int n = r2 >> 7, k = r2 & 127;
    val = Wo[i * 16384 + k * 128 + n];
  } else if (r < 98304) {
    const int r2 = r - 65536;
    const int n = r2 >> 7, k = r2 & 127;
    val = W1[i * 32768 + k * 256 + n];
  } else {
    const int r2 = r - 98304;
    const int n = r2 >> 8, k = r2 & 255;
    val = W2[i * 32768 + k * 128 + n];
  }
  wt[idx] = (f16)val;
}

// ---------------- QKV projection via MFMA (layer 0 only) ------------------
__global__ __launch_bounds__(256) void qkv_kernel(
    const f16* __restrict__ xh, const f16* __restrict__ wqkvT,
    f16* __restrict__ qh, f16* __restrict__ kh, f16* __restrict__ vth) {
  const int t = threadIdx.x;
  const int wave = t >> 6, lane = t & 63;
  const int g = lane >> 4, c = lane & 15;
  const int r0g = blockIdx.x * 64 + wave * 16;
  const int b4 = (r0g >> 11) * 4;
  const int l0 = r0g & 2047;

  f16x8 a[4];
#pragma unroll
  for (int kt = 0; kt < 4; ++kt)
    a[kt] = *(const f16x8*)(xh + (size_t)(r0g + c) * 128 + kt * 32 + g * 8);

#pragma unroll
  for (int sel = 0; sel < 2; ++sel) {
    const f16* wT = wqkvT + sel * 16384;
    f16* out = (sel == 0) ? qh : kh;
#pragma unroll
    for (int nt = 0; nt < 8; ++nt) {
      f32x4 acc = {0.f, 0.f, 0.f, 0.f};
#pragma unroll
      for (int kt = 0; kt < 4; ++kt) {
        f16x8 bfrag = *(const f16x8*)(wT + (nt * 16 + c) * 128 + kt * 32 + g * 8);
        acc = __builtin_amdgcn_mfma_f32_16x16x32_f16(a[kt], bfrag, acc, 0, 0, 0);
      }
      const int h = nt >> 1, e = (nt & 1) * 16 + c;
#pragma unroll
      for (int r = 0; r < 4; ++r)
        out[((size_t)(b4 + h) * LL + l0 + 4 * g + r) * DKK + e] = (f16)acc[r];
    }
  }
  {
    const f16* wT = wqkvT + 2 * 16384;
#pragma unroll
    for (int nt = 0; nt < 8; ++nt) {
      f32x4 acc = {0.f, 0.f, 0.f, 0.f};
#pragma unroll
      for (int kt = 0; kt < 4; ++kt) {
        f16x8 afrag = *(const f16x8*)(wT + (nt * 16 + c) * 128 + kt * 32 + g * 8);
        acc = __builtin_amdgcn_mfma_f32_16x16x32_f16(afrag, a[kt], acc, 0, 0, 0);
      }
#pragma unroll
      for (int r = 0; r < 4; ++r) {
        const int eg = nt * 16 + 4 * g + r;
        vth[((size_t)(b4 + (eg >> 5)) * DKK + (eg & 31)) * LL + l0 + c] =
            (f16)acc[r];
      }
    }
  }
}

// ---------------- Flash attention, KVB=64, S^T layout, low-VGPR ----------
__global__ __launch_bounds__(256) void attn_kernel(
    const f16* __restrict__ qh, const f16* __restrict__ kh,
    const f16* __restrict__ vth, const float* __restrict__ mask,
    f16* __restrict__ o) {
  __shared__ f16 Ks[2][64][40];
  __shared__ f16 Vt[2][32][72];
  __shared__ float mks[2][64];
  __shared__ int mkflag[2];
  const int t = threadIdx.x;
  const int wave = t >> 6, lane = t & 63;
  const int g = lane >> 4, c = lane & 15;

  // XCD-aware remap: 16 consecutive slots (q-blocks of one bh) per XCD
  const int flat = blockIdx.y * 16 + blockIdx.x;
  const int xcd = flat & 7, slot = flat >> 3;
  const int bh = xcd * 4 + (slot >> 4);
  const int qb = slot & 15;
  const int b = bh >> 2;
  const int qw = qb * 128 + wave * 32;

  f16x8 qfrag[2];
  float mqv[2];
#pragma unroll
  for (int qt = 0; qt < 2; ++qt) {
    qfrag[qt] =
        *(const f16x8*)(qh + ((size_t)bh * LL + qw + qt * 16 + c) * DKK + g * 8);
    mqv[qt] = mask[b * LL + qw + qt * 16 + c];
  }
  const bool qflag = __all(mqv[0] == 1.f && mqv[1] == 1.f);

  f32x4 o4[2][2];
  float m[2], l[2];
#pragma unroll
  for (int qt = 0; qt < 2; ++qt) {
    m[qt] = -3.0e38f; l[qt] = 0.f;
#pragma unroll
    for (int dt = 0; dt < 2; ++dt)
#pragma unroll
      for (int r = 0; r < 4; ++r) o4[qt][dt][r] = 0.f;
  }

  const f16* kbase = kh + (size_t)bh * LL * DKK;
  const f16* vbase = vth + (size_t)bh * DKK * LL;
  const int krow = t >> 2, kch = t & 3;
  const int vd = t >> 3, vseg = t & 7;

  f16x8 kreg = *(const f16x8*)(kbase + (size_t)krow * DKK + kch * 8);
  f16x8 vreg = *(const f16x8*)(vbase + (size_t)vd * LL + vseg * 8);
  float mreg = (t < 64) ? mask[b * LL + t] : 1.f;
  *(f16x8*)&Ks[0][krow][kch * 8] = kreg;
  *(f16x8*)&Vt[0][vd][vseg * 8] = vreg;
  if (t < 64) mks[0][t] = mreg;
  if (wave == 0) {
    unsigned long long ok = __ballot(mreg == 1.f);
    if (lane == 0) mkflag[0] = (ok == ~0ull);
  }
  __syncthreads();

  for (int kt = 0; kt < LL / 64; ++kt) {
    const int cur = kt & 1;
    if (kt < LL / 64 - 1) {
      const int k0 = (kt + 1) * 64;
      kreg = *(const f16x8*)(kbase + (size_t)(k0 + krow) * DKK + kch * 8);
      vreg = *(const f16x8*)(vbase + (size_t)vd * LL + k0 + vseg * 8);
      mreg = (t < 64) ? mask[b * LL + k0 + t] : 1.f;
    }
    const bool nomask = qflag && mkflag[cur];

    // ---- fragments ----
    f16x8 kb[4];
#pragma unroll
    for (int nt = 0; nt < 4; ++nt)
      kb[nt] = *(const f16x8*)&Ks[cur][nt * 16 + c][g * 8];
    f16x4 va[2][4];
#pragma unroll
    for (int dt = 0; dt < 2; ++dt)
#pragma unroll
      for (int nt = 0; nt < 4; ++nt)
        va[dt][nt] = *(const f16x4*)&Vt[cur][dt * 16 + c][nt * 16 + 4 * g];

    // ---- QK^T both q-tiles (MFMA cluster) ----
    f32x4 st[2][4];
    __builtin_amdgcn_s_setprio(1);
#pragma unroll
    for (int qt = 0; qt < 2; ++qt)
#pragma unroll
      for (int nt = 0; nt < 4; ++nt) {
        f32x4 z = {0.f, 0.f, 0.f, 0.f};
        st[qt][nt] =
            __builtin_amdgcn_mfma_f32_16x16x32_f16(kb[nt], qfrag[qt], z, 0, 0, 0);
      }
    __builtin_amdgcn_s_setprio(0);

    if (!nomask) {
#pragma unroll
      for (int qt = 0; qt < 2; ++qt) {
        const float mq = mqv[qt];
#pragma unroll
        for (int nt = 0; nt < 4; ++nt) {
          float4 mk4 = *(const float4*)&mks[cur][nt * 16 + 4 * g];
          st[qt][nt][0] += (1.f - mq * mk4.x) * NEGMIN;
          st[qt][nt][1] += (1.f - mq * mk4.y) * NEGMIN;
          st[qt][nt][2] += (1.f - mq * mk4.z) * NEGMIN;
          st[qt][nt][3] += (1.f - mq * mk4.w) * NEGMIN;
        }
      }
    }

#pragma unroll
    for (int qt = 0; qt < 2; ++qt) {
      // row max: 15 fmax + 2 shfl
      float vmax = fmaxf(fmaxf(st[qt][0][0], st[qt][0][1]),
                         fmaxf(st[qt][0][2], st[qt][0][3]));
#pragma unroll
      for (int nt = 1; nt < 4; ++nt)
        vmax = fmaxf(vmax, fmaxf(fmaxf(st[qt][nt][0], st[qt][nt][1]),
                                 fmaxf(st[qt][nt][2], st[qt][nt][3])));
      vmax = fmaxf(vmax, __shfl_xor(vmax, 16));
      vmax = fmaxf(vmax, __shfl_xor(vmax, 32));

      // defer-max: only rescale when growth > 8
      if (!__all(vmax - m[qt] <= 8.f)) {
        const float mn = fmaxf(m[qt], vmax);
        const float sc = __builtin_exp2f((m[qt] - mn) * LOG2E);
        l[qt] *= sc;
#pragma unroll
        for (int dt = 0; dt < 2; ++dt)
#pragma unroll
          for (int r = 0; r < 4; ++r) o4[qt][dt][r] *= sc;
        m[qt] = mn;
      }
      const float mn2 = m[qt] * LOG2E;

      // exp + per-lane partial l (no per-tile shfl)
      float p[4][4];
      float psum = 0.f;
#pragma unroll
      for (int nt = 0; nt < 4; ++nt) {
#pragma unroll
        for (int r = 0; r < 4; ++r) {
          p[nt][r] = __builtin_exp2f(fmaf(st[qt][nt][r], LOG2E, -mn2));
          psum += p[nt][r];
        }
      }
      l[qt] += psum;

      // pack + PV (MFMA cluster)
      __builtin_amdgcn_s_setprio(1);
#pragma unroll
      for (int nt = 0; nt < 4; ++nt) {
        PKU pk;
        pk.h2[0] = __builtin_amdgcn_cvt_pkrtz(p[nt][0], p[nt][1]);
        pk.h2[1] = __builtin_amdgcn_cvt_pkrtz(p[nt][2], p[nt][3]);
        o4[qt][0] = __builtin_amdgcn_mfma_f32_16x16x16f16(va[0][nt], pk.v,
                                                          o4[qt][0], 0, 0, 0);
        o4[qt][1] = __builtin_amdgcn_mfma_f32_16x16x16f16(va[1][nt], pk.v,
                                                          o4[qt][1], 0, 0, 0);
      }
      __builtin_amdgcn_s_setprio(0);
    }

    if (kt < LL / 64 - 1) {
      *(f16x8*)&Ks[1 - cur][krow][kch * 8] = kreg;
      *(f16x8*)&Vt[1 - cur][vd][vseg * 8] = vreg;
      if (t < 64) mks[1 - cur][t] = mreg;
      if (wave == 0) {
        unsigned long long ok = __ballot(mreg == 1.f);
        if (lane == 0) mkflag[1 - cur] = (ok == ~0ull);
      }
    }
    __syncthreads();
  }

  // ---- epilogue: reduce l across the 4 g-lanes, write f16 o ----
  const int h = bh & 3;
#pragma unroll
  for (int qt = 0; qt < 2; ++qt) {
    float lt = l[qt];
    lt += __shfl_xor(lt, 16);
    lt += __shfl_xor(lt, 32);
    const float rdiv = 1.f / lt;
    f16* orow = o + ((size_t)b * LL + qw + qt * 16 + c) * DD + h * DKK;
#pragma unroll
    for (int dt = 0; dt < 2; ++dt) {
      f16x4 res;
      res[0] = (f16)(o4[qt][dt][0] * rdiv);
      res[1] = (f16)(o4[qt][dt][1] * rdiv);
      res[2] = (f16)(o4[qt][dt][2] * rdiv);
      res[3] = (f16)(o4[qt][dt][3] * rdiv);
      *(f16x4*)(orow + dt * 16 + g * 4) = res;
    }
  }
}

// ---------------- MFMA MLP (+ optional fused next-layer QKV) --------------
__global__ __launch_bounds__(256) void mlp_kernel(
    const f16* __restrict__ o, const float* __restrict__ x,
    const f16* __restrict__ WoT, const f16* __restrict__ W1T,
    const f16* __restrict__ W2T, const float* __restrict__ b1,
    const float* __restrict__ b2, float* __restrict__ xout,
    const f16* __restrict__ wqkvT_next,
    f16* __restrict__ qh, f16* __restrict__ kh, f16* __restrict__ vth) {
  __shared__ f16 Xm[64][136];
  __shared__ f16 Fs[64][264];
  const int t = threadIdx.x;
  const int wave = t >> 6, lane = t & 63;
  const int g = lane >> 4, c = lane & 15;
  const int mrow = wave * 16;
  const long r0 = (long)blockIdx.x * 64;

  // ---- step1: xm = (o @ Wo + x) * 0.5 ----
  f16x8 a1[4];
#pragma unroll
  for (int kt = 0; kt < 4; ++kt)
    a1[kt] = *(const f16x8*)(o + (r0 + mrow + c) * 128 + kt * 32 + g * 8);

  f32x4 xmreg[8];
#pragma unroll
  for (int nt = 0; nt < 8; ++nt) {
    f32x4 acc = {0.f, 0.f, 0.f, 0.f};
#pragma unroll
    for (int kt = 0; kt < 4; ++kt) {
      f16x8 bfrag = *(const f16x8*)(WoT + (nt * 16 + c) * 128 + kt * 32 + g * 8);
      acc = __builtin_amdgcn_mfma_f32_16x16x32_f16(a1[kt], bfrag, acc, 0, 0, 0);
    }
#pragma unroll
    for (int r = 0; r < 4; ++r) {
      const float xv = x[(r0 + mrow + 4 * g + r) * 128 + nt * 16 + c];
      acc[r] = (acc[r] + xv) * 0.5f;
      Xm[mrow + 4 * g + r][nt * 16 + c] = (f16)acc[r];
    }
    xmreg[nt] = acc;
  }

  // ---- step2: f = gelu(xm @ W1 + b1) ----
  f16x8 a2[4];
#pragma unroll
  for (int kt = 0; kt < 4; ++kt)
    a2[kt] = *(const f16x8*)&Xm[mrow + c][kt * 32 + g * 8];
#pragma unroll
  for (int nt = 0; nt < 16; ++nt) {
    f32x4 acc = {0.f, 0.f, 0.f, 0.f};
#pragma unroll
    for (int kt = 0; kt < 4; ++kt) {
      f16x8 bfrag = *(const f16x8*)(W1T + (nt * 16 + c) * 128 + kt * 32 + g * 8);
      acc = __builtin_amdgcn_mfma_f32_16x16x32_f16(a2[kt], bfrag, acc, 0, 0, 0);
    }
    const float bj = b1[nt * 16 + c];
#pragma unroll
    for (int r = 0; r < 4; ++r) {
      const float val = acc[r] + bj;
      Fs[mrow + 4 * g + r][nt * 16 + c] =
          (f16)(0.5f * val * (1.f + erff(val * 0.70710678118654752f)));
    }
  }

  // ---- step3: out = (f @ W2 + b2 + xm) * 0.5 ----
  f16x8 a3[8];
#pragma unroll
  for (int kt = 0; kt < 8; ++kt)
    a3[kt] = *(const f16x8*)&Fs[mrow + c][kt * 32 + g * 8];
#pragma unroll
  for (int nt = 0; nt < 8; ++nt) {
    f32x4 acc = {0.f, 0.f, 0.f, 0.f};
#pragma unroll
    for (int kt = 0; kt < 8; ++kt) {
      f16x8 bfrag = *(const f16x8*)(W2T + (nt * 16 + c) * 256 + kt * 32 + g * 8);
      acc = __builtin_amdgcn_mfma_f32_16x16x32_f16(a3[kt], bfrag, acc, 0, 0, 0);
    }
    const float bj = b2[nt * 16 + c];
#pragma unroll
    for (int r = 0; r < 4; ++r) {
      const float val = (acc[r] + bj + xmreg[nt][r]) * 0.5f;
      xout[(r0 + mrow + 4 * g + r) * 128 + nt * 16 + c] = val;
      Xm[mrow + 4 * g + r][nt * 16 + c] = (f16)val;  // reuse Xm as xh_next
    }
  }

  // ---- step4 (optional): next layer's QKV from Xm (wave-local rows) ----
  if (wqkvT_next) {
    const int r0g = (int)r0 + mrow;
    const int b4 = (r0g >> 11) * 4;
    const int l0 = r0g & 2047;
    f16x8 a[4];
#pragma unroll
    for (int kt = 0; kt < 4; ++kt)
      a[kt] = *(const f16x8*)&Xm[mrow + c][kt * 32 + g * 8];

#pragma unroll
    for (int sel = 0; sel < 2; ++sel) {
      const f16* wT = wqkvT_next + sel * 16384;
      f16* out = (sel == 0) ? qh : kh;
#pragma unroll
      for (int nt = 0; nt < 8; ++nt) {
        f32x4 acc = {0.f, 0.f, 0.f, 0.f};
#pragma unroll
        for (int kt = 0; kt < 4; ++kt) {
          f16x8 bfrag =
              *(const f16x8*)(wT + (nt * 16 + c) * 128 + kt * 32 + g * 8);
          acc = __builtin_amdgcn_mfma_f32_16x16x32_f16(a[kt], bfrag, acc, 0, 0, 0);
        }
        const int h = nt >> 1, e = (nt & 1) * 16 + c;
#pragma unroll
        for (int r = 0; r < 4; ++r)
          out[((size_t)(b4 + h) * LL + l0 + 4 * g + r) * DKK + e] = (f16)acc[r];
      }
    }
    {
      const f16* wT = wqkvT_next + 2 * 16384;
#pragma unroll
      for (int nt = 0; nt < 8; ++nt) {
        f32x4 acc = {0.f, 0.f, 0.f, 0.f};
#pragma unroll
        for (int kt = 0; kt < 4; ++kt) {
          f16x8 afrag =
              *(const f16x8*)(wT + (nt * 16 + c) * 128 + kt * 32 + g * 8);
          acc = __builtin_amdgcn_mfma_f32_16x16x32_f16(afrag, a[kt], acc, 0, 0, 0);
        }
#pragma unroll
        for (int r = 0; r < 4; ++r) {
          const int eg = nt * 16 + 4 * g + r;
          vth[((size_t)(b4 + (eg >> 5)) * DKK + (eg & 31)) * LL + l0 + c] =
              (f16)acc[r];
        }
      }
    }
  }
}

extern "C" void kernel_launch(void* const* d_in, const int* in_sizes, int n_in,
                              void* d_out, int out_size, void* d_ws,
                              size_t ws_size, hipStream_t stream) {
  const float* x    = (const float*)d_in[0];
  const float* mask = (const float*)d_in[1];
  const float* Wq   = (const float*)d_in[2];
  const float* Wk   = (const float*)d_in[3];
  const float* Wv   = (const float*)d_in[4];
  const float* Wo   = (const float*)d_in[5];
  const float* W1   = (const float*)d_in[6];
  const float* b1   = (const float*)d_in[7];
  const float* W2   = (const float*)d_in[8];
  const float* b2   = (const float*)d_in[9];

  const size_t SZ = (size_t)BB * LL * DD;
  char* p = (char*)d_ws;
  f16* qh   = (f16*)p;  p += SZ * sizeof(f16);
  f16* kh   = (f16*)p;  p += SZ * sizeof(f16);
  f16* vth  = (f16*)p;  p += SZ * sizeof(f16);
  f16* ob   = (f16*)p;  p += SZ * sizeof(f16);
  f16* xh0  = (f16*)p;  p += SZ * sizeof(f16);
  f16* wt   = (f16*)p;  p += (size_t)262144 * sizeof(f16);
  float* xA = (float*)p;

  wconv_kernel<<<1024, 256, 0, stream>>>(Wq, Wk, Wv, Wo, W1, W2, wt);
  xcvt_kernel<<<SZ / 8 / 256, 256, 0, stream>>>(x, xh0);

  for (int i = 0; i < 2; ++i) {
    const float* xin = (i == 0) ? x : xA;
    float* xout = (i == 1) ? (float*)d_out : xA;
    const f16* qkvT_i = wt + (size_t)i * 131072;
    const f16* WoT_i  = wt + (size_t)i * 131072 + 49152;
    const f16* W1T_i  = wt + (size_t)i * 131072 + 65536;
    const f16* W2T_i  = wt + (size_t)i * 131072 + 98304;
    const float* b1_i = b1 + (long)i * DFFF;
    const float* b2_i = b2 + (long)i * DD;
    const f16* qkvT_next = (i == 0) ? (wt + 131072) : nullptr;

    if (i == 0)
      qkv_kernel<<<(BB * LL) / 64, 256, 0, stream>>>(xh0, qkvT_i, qh, kh, vth);
    attn_kernel<<<dim3(LL / 128, BB * HH), 256, 0, stream>>>(qh, kh, vth, mask, ob);
    mlp_kernel<<<(BB * LL) / 64, 256, 0, stream>>>(ob, xin, WoT_i, W1T_i, W2T_i,
                                                   b1_i, b2_i, xout,
                                                   qkvT_next, qh, kh, vth);
  }
}